// Round 2
// baseline (158.214 us; speedup 1.0000x reference)
//
#include <hip/hip_runtime.h>
#include <math.h>

#define NB 32
#define NN 4096
#define NK 16
#define ND 128

#define W_STD 0.01f
#define W_REC 1.0
#define W_SPS 0.1
#define W_EXT 0.01
#define W_KLD 0.001
#define W_CST 0.1

__device__ __forceinline__ float sgnpow(float v, float m) {
    // sign(v) * |v|^m  (m > 0; __powf(0,m)=0 so v=0 -> 0)
    return copysignf(__powf(fabsf(v), m), v);
}

// One thread = one point n (for fixed b); loops all K=16 primitives.
// Writes per-block REC partial and per-block assign-column-sum partials.
__global__ __launch_bounds__(256) void rec_kernel(
    const float* __restrict__ pc, const float* __restrict__ normals,
    const float* __restrict__ rnd, const float* __restrict__ scale,
    const float* __restrict__ shapes, const float* __restrict__ rotate,
    const float* __restrict__ mean, const float* __restrict__ assign,
    float* __restrict__ recpart, float* __restrict__ colpart)
{
    const int b     = blockIdx.x >> 4;   // 16 chunks per batch
    const int chunk = blockIdx.x & 15;
    const int t     = threadIdx.x;
    const int n     = chunk * 256 + t;

    __shared__ float sR[NK*9], sS[NK*3], sE[NK*2], sM[NK*3];
    __shared__ float csum[4][NK];
    __shared__ float wsum[4];

    for (int i = t; i < 272; i += 256) {
        if (i < 144)      sR[i]     = rotate[b*144 + i];
        else if (i < 192) sS[i-144] = scale [b*48  + (i-144)];
        else if (i < 224) sE[i-192] = shapes[b*32  + (i-192)];
        else              sM[i-224] = mean  [b*48  + (i-224)];
    }
    __syncthreads();

    const long pbase = (long)(b*NN + n);
    const float px = pc[pbase*3+0], py = pc[pbase*3+1], pz = pc[pbase*3+2];
    const float nx = normals[pbase*3+0], ny = normals[pbase*3+1], nz = normals[pbase*3+2];
    const float noise = rnd[pbase] * W_STD;

    const float4* arow = (const float4*)(assign + pbase*16);
    float4 a0 = arow[0], a1 = arow[1], a2 = arow[2], a3 = arow[3];
    float a[16] = {a0.x,a0.y,a0.z,a0.w, a1.x,a1.y,a1.z,a1.w,
                   a2.x,a2.y,a2.z,a2.w, a3.x,a3.y,a3.z,a3.w};

    const float inn = rsqrtf(nx*nx + ny*ny + nz*nz);
    const float ux = nx*inn, uy = ny*inn, uz = nz*inn;            // unit normal
    const float qx = px + noise*nx, qy = py + noise*ny, qz = pz + noise*nz; // pc_sample

    const int wave = t >> 6, lane = t & 63;
    float rec = 0.f;

    #pragma unroll
    for (int k = 0; k < NK; ++k) {
        const float R0 = sR[k*9+0], R1 = sR[k*9+1], R2 = sR[k*9+2];
        const float R3 = sR[k*9+3], R4 = sR[k*9+4], R5 = sR[k*9+5];
        const float R6 = sR[k*9+6], R7 = sR[k*9+7], R8 = sR[k*9+8];
        const float cx = sM[k*3], cy = sM[k*3+1], cz = sM[k*3+2];
        const float s0 = sS[k*3], s1 = sS[k*3+1], s2 = sS[k*3+2];
        const float e0 = sE[k*2], e1 = sE[k*2+1];

        // psi = R^T (pc_sample - mean)
        float vx = qx-cx, vy = qy-cy, vz = qz-cz;
        float psx = R0*vx + R3*vy + R6*vz;
        float psy = R1*vx + R4*vy + R7*vz;
        float psz = R2*vx + R5*vy + R8*vz;
        // pci = R^T (pc - mean)
        float wx = px-cx, wy = py-cy, wz = pz-cz;
        float pcx = R0*wx + R3*wy + R6*wz;
        float pcy = R1*wx + R4*wy + R7*wz;
        float pcz = R2*wx + R5*wy + R8*wz;
        // ni = R^T unit_normal
        float nix = R0*ux + R3*uy + R6*uz;
        float niy = R1*ux + R4*uy + R7*uz;
        float niz = R2*ux + R5*uy + R8*uz;

        // argmax over [-nix, nix, -niy, niy, -niz, niz], first-max wins
        float best = -nix; int idx = 0;
        if ( nix > best) { best =  nix; idx = 1; }
        if (-niy > best) { best = -niy; idx = 2; }
        if ( niy > best) { best =  niy; idx = 3; }
        if (-niz > best) { best = -niz; idx = 4; }
        if ( niz > best) { best =  niz; idx = 5; }

        float sx = fminf(fmaxf(psx, -s0), s0);
        float sy = fminf(fmaxf(psy, -s1), s1);
        float sz = fminf(fmaxf(psz, -s2), s2);
        const float sgn = (idx & 1) ? 1.f : -1.f;
        const int axis = idx >> 1;
        if (axis == 0)      sx = sgn*s0;
        else if (axis == 1) sy = sgn*s1;
        else                sz = sgn*s2;

        // trig-free: cos/sin of theta=atan2(sy,sx), phi=atan2(sz, rxy)
        float hx   = sx*sx + sy*sy;
        float irxy = (hx > 0.f) ? rsqrtf(hx) : 0.f;
        float ct   = (hx > 0.f) ? sx*irxy : 1.f;
        float st   = sy*irxy;           // 0 when hx==0
        float rxy  = hx*irxy;           // sqrt(hx), 0 when hx==0
        float r3sq = hx + sz*sz;        // >= s_axis^2 >= 0.01
        float ir3  = rsqrtf(r3sq);
        float cphi = rxy*ir3;           // >= 0
        float sphi = sz*ir3;

        float gphi = __powf(cphi, e0);  // cphi >= 0
        float fphi = sgnpow(sphi, e0);
        float gth  = sgnpow(ct, e1);
        float fth  = sgnpow(st, e1);

        float X = s0*gphi*gth;
        float Y = s1*gphi*fth;
        float Z = s2*fphi;
        float dx = X-pcx, dy = Y-pcy, dz = Z-pcz;
        rec += (dx*dx + dy*dy + dz*dz) * a[k];

        // column-sum partial for this k: wave butterfly
        float v = a[k];
        #pragma unroll
        for (int o = 32; o; o >>= 1) v += __shfl_xor(v, o);
        if (lane == 0) csum[wave][k] = v;
    }

    // block-reduce rec
    #pragma unroll
    for (int o = 32; o; o >>= 1) rec += __shfl_xor(rec, o);
    if (lane == 0) wsum[wave] = rec;
    __syncthreads();
    if (t == 0) recpart[blockIdx.x] = wsum[0] + wsum[1] + wsum[2] + wsum[3];
    if (t < NK) colpart[blockIdx.x*NK + t] = csum[0][t] + csum[1][t] + csum[2][t] + csum[3][t];
}

// Single block: column sums -> SPS/EXT; KLD; CST; REC sum; weighted combine.
__global__ __launch_bounds__(256) void finalize_kernel(
    const float* __restrict__ exist, const float* __restrict__ mu,
    const float* __restrict__ logvar, const float* __restrict__ mean,
    const float* __restrict__ trans, const float* __restrict__ recpart,
    const float* __restrict__ colpart, float* __restrict__ out)
{
    const int t = threadIdx.x;
    __shared__ float scol[NB*NK];
    __shared__ double red[256];

    // column sums: colsum[b][k] = sum over 16 chunks of colpart[(b*16+c)*16 + k]
    for (int i = t; i < NB*NK; i += 256) {
        int b = i >> 4, k = i & 15;
        float s = 0.f;
        #pragma unroll
        for (int c = 0; c < 16; ++c) s += colpart[(b*16 + c)*16 + k];
        scol[i] = s;
    }
    __syncthreads();

    double acc = 0.0;

    // KLD: mean_b( -0.5 * sum_d(1 + lv - mu^2 - e^lv) )
    for (int i = t; i < NB*ND; i += 256) {
        float lv = logvar[i], m = mu[i];
        acc += (double)(-0.5f * (1.0f + lv - m*m - expf(lv))) * (W_KLD / (double)NB);
    }

    // EXT + CST + REC over 512 per-(b,k)/per-block slots
    for (int i = t; i < NB*NK; i += 256) {
        float l  = exist[i];
        float gt = (scol[i] > 24.0f) ? 1.0f : 0.0f;
        float ext = fmaxf(l, 0.f) - l*gt + log1pf(expf(-fabsf(l)));
        acc += (double)ext * (W_EXT / (double)(NB*NK));

        float dx = mean[i*3+0] - trans[i*3+0];
        float dy = mean[i*3+1] - trans[i*3+1];
        float dz = mean[i*3+2] - trans[i*3+2];
        acc += (double)sqrtf(dx*dx + dy*dy + dz*dz) * (W_CST / (double)(NB*NK));

        acc += (double)recpart[i] * (W_REC / ((double)NB * (double)NN));
    }

    // SPS: mean_b( (mean_k sqrt(colsum/N + 0.01))^2 )
    if (t < NB) {
        float sm = 0.f;
        #pragma unroll
        for (int k = 0; k < NK; ++k)
            sm += sqrtf(scol[t*NK + k] * (1.0f/(float)NN) + 0.01f);
        sm *= (1.0f/(float)NK);
        acc += (double)(sm*sm) * (W_SPS / (double)NB);
    }

    red[t] = acc;
    __syncthreads();
    for (int s2 = 128; s2; s2 >>= 1) {
        if (t < s2) red[t] += red[t + s2];
        __syncthreads();
    }
    if (t == 0) out[0] = (float)red[0];
}

extern "C" void kernel_launch(void* const* d_in, const int* in_sizes, int n_in,
                              void* d_out, int out_size, void* d_ws, size_t ws_size,
                              hipStream_t stream) {
    const float* pc      = (const float*)d_in[0];
    const float* normals = (const float*)d_in[1];
    const float* rnd     = (const float*)d_in[2];
    const float* scale   = (const float*)d_in[3];
    const float* shapes  = (const float*)d_in[4];
    const float* rotate  = (const float*)d_in[5];
    const float* mean    = (const float*)d_in[6];
    const float* assign  = (const float*)d_in[7];
    const float* exist   = (const float*)d_in[8];
    const float* mu      = (const float*)d_in[9];
    const float* logvar  = (const float*)d_in[10];
    const float* trans   = (const float*)d_in[11];

    float* recpart = (float*)d_ws;            // 512 floats, all written each call
    float* colpart = recpart + NB*16;         // 512*16 floats, all written each call

    rec_kernel<<<dim3(NB*16), dim3(256), 0, stream>>>(
        pc, normals, rnd, scale, shapes, rotate, mean, assign, recpart, colpart);
    finalize_kernel<<<dim3(1), dim3(256), 0, stream>>>(
        exist, mu, logvar, mean, trans, recpart, colpart, (float*)d_out);
}

// Round 3
// 109.489 us; speedup vs baseline: 1.4450x; 1.4450x over previous
//
#include <hip/hip_runtime.h>
#include <math.h>

#define NB 32
#define NN 4096
#define NK 16
#define ND 128

#define W_STD 0.01f
#define W_REC 1.0
#define W_SPS 0.1
#define W_EXT 0.01
#define W_KLD 0.001
#define W_CST 0.1

// Native gfx950 transcendentals: v_log_f32 (log2), v_exp_f32 (2^x), v_rsq_f32.
__device__ __forceinline__ float fast_rsqrt(float x) { return __builtin_amdgcn_rsqf(x); }
__device__ __forceinline__ float fast_pow(float x, float m) {
    // x >= 0; x==0 -> log2=-inf -> exp2(-inf)=0 (m>0), matching |0|^m=0
    return __builtin_amdgcn_exp2f(m * __builtin_amdgcn_logf(x));
}
__device__ __forceinline__ float sgnpow(float v, float m) {
    return copysignf(fast_pow(fabsf(v), m), v);
}

// One thread = one point n (for fixed b); loops all K=16 primitives.
// Writes per-block REC partial and per-block assign-column-sum partials.
__global__ __launch_bounds__(256) void rec_kernel(
    const float* __restrict__ pc, const float* __restrict__ normals,
    const float* __restrict__ rnd, const float* __restrict__ scale,
    const float* __restrict__ shapes, const float* __restrict__ rotate,
    const float* __restrict__ mean, const float* __restrict__ assign,
    float* __restrict__ recpart, float* __restrict__ colpart)
{
    const int b     = blockIdx.x >> 4;   // 16 chunks per batch
    const int chunk = blockIdx.x & 15;
    const int t     = threadIdx.x;
    const int n     = chunk * 256 + t;

    __shared__ float sR[NK*9], sS[NK*3], sE[NK*2], sM[NK*3];
    __shared__ float csum[4][NK];
    __shared__ float wsum[4];

    for (int i = t; i < 272; i += 256) {
        if (i < 144)      sR[i]     = rotate[b*144 + i];
        else if (i < 192) sS[i-144] = scale [b*48  + (i-144)];
        else if (i < 224) sE[i-192] = shapes[b*32  + (i-192)];
        else              sM[i-224] = mean  [b*48  + (i-224)];
    }
    __syncthreads();

    const long pbase = (long)(b*NN + n);
    const float px = pc[pbase*3+0], py = pc[pbase*3+1], pz = pc[pbase*3+2];
    const float nx = normals[pbase*3+0], ny = normals[pbase*3+1], nz = normals[pbase*3+2];
    const float noise = rnd[pbase] * W_STD;

    const float4* arow = (const float4*)(assign + pbase*16);
    float4 a0 = arow[0], a1 = arow[1], a2 = arow[2], a3 = arow[3];
    float a[16] = {a0.x,a0.y,a0.z,a0.w, a1.x,a1.y,a1.z,a1.w,
                   a2.x,a2.y,a2.z,a2.w, a3.x,a3.y,a3.z,a3.w};

    const float inn = fast_rsqrt(nx*nx + ny*ny + nz*nz);
    const float ux = nx*inn, uy = ny*inn, uz = nz*inn;            // unit normal
    const float qx = px + noise*nx, qy = py + noise*ny, qz = pz + noise*nz; // pc_sample

    const int wave = t >> 6, lane = t & 63;
    float rec = 0.f;

    #pragma unroll
    for (int k = 0; k < NK; ++k) {
        const float R0 = sR[k*9+0], R1 = sR[k*9+1], R2 = sR[k*9+2];
        const float R3 = sR[k*9+3], R4 = sR[k*9+4], R5 = sR[k*9+5];
        const float R6 = sR[k*9+6], R7 = sR[k*9+7], R8 = sR[k*9+8];
        const float cx = sM[k*3], cy = sM[k*3+1], cz = sM[k*3+2];
        const float s0 = sS[k*3], s1 = sS[k*3+1], s2 = sS[k*3+2];
        const float e0 = sE[k*2], e1 = sE[k*2+1];

        // psi = R^T (pc_sample - mean)
        float vx = qx-cx, vy = qy-cy, vz = qz-cz;
        float psx = R0*vx + R3*vy + R6*vz;
        float psy = R1*vx + R4*vy + R7*vz;
        float psz = R2*vx + R5*vy + R8*vz;
        // pci = R^T (pc - mean)
        float wx = px-cx, wy = py-cy, wz = pz-cz;
        float pcx = R0*wx + R3*wy + R6*wz;
        float pcy = R1*wx + R4*wy + R7*wz;
        float pcz = R2*wx + R5*wy + R8*wz;
        // ni = R^T unit_normal
        float nix = R0*ux + R3*uy + R6*uz;
        float niy = R1*ux + R4*uy + R7*uz;
        float niz = R2*ux + R5*uy + R8*uz;

        // argmax over [-nix, nix, -niy, niy, -niz, niz], first-max wins
        float best = -nix; int idx = 0;
        if ( nix > best) { best =  nix; idx = 1; }
        if (-niy > best) { best = -niy; idx = 2; }
        if ( niy > best) { best =  niy; idx = 3; }
        if (-niz > best) { best = -niz; idx = 4; }
        if ( niz > best) { best =  niz; idx = 5; }

        float sx = fminf(fmaxf(psx, -s0), s0);
        float sy = fminf(fmaxf(psy, -s1), s1);
        float sz = fminf(fmaxf(psz, -s2), s2);
        const float sgn = (idx & 1) ? 1.f : -1.f;
        const int axis = idx >> 1;
        if (axis == 0)      sx = sgn*s0;
        else if (axis == 1) sy = sgn*s1;
        else                sz = sgn*s2;

        // trig-free: cos/sin of theta=atan2(sy,sx), phi=atan2(sz, rxy)
        float hx   = sx*sx + sy*sy;
        float irxy = (hx > 0.f) ? fast_rsqrt(hx) : 0.f;
        float ct   = (hx > 0.f) ? sx*irxy : 1.f;
        float st   = sy*irxy;           // 0 when hx==0
        float rxy  = hx*irxy;           // sqrt(hx), 0 when hx==0
        float r3sq = hx + sz*sz;        // >= s_axis^2 >= 0.01
        float ir3  = fast_rsqrt(r3sq);
        float cphi = rxy*ir3;           // >= 0
        float sphi = sz*ir3;

        float gphi = fast_pow(cphi, e0); // cphi >= 0
        float fphi = sgnpow(sphi, e0);
        float gth  = sgnpow(ct, e1);
        float fth  = sgnpow(st, e1);

        float X = s0*gphi*gth;
        float Y = s1*gphi*fth;
        float Z = s2*fphi;
        float dx = X-pcx, dy = Y-pcy, dz = Z-pcz;
        rec += (dx*dx + dy*dy + dz*dz) * a[k];

        // column-sum partial for this k: wave butterfly
        float v = a[k];
        #pragma unroll
        for (int o = 32; o; o >>= 1) v += __shfl_xor(v, o);
        if (lane == 0) csum[wave][k] = v;
    }

    // block-reduce rec
    #pragma unroll
    for (int o = 32; o; o >>= 1) rec += __shfl_xor(rec, o);
    if (lane == 0) wsum[wave] = rec;
    __syncthreads();
    if (t == 0) recpart[blockIdx.x] = wsum[0] + wsum[1] + wsum[2] + wsum[3];
    if (t < NK) colpart[blockIdx.x*NK + t] = csum[0][t] + csum[1][t] + csum[2][t] + csum[3][t];
}

// Single block: column sums -> SPS/EXT; KLD; CST; REC sum; weighted combine.
__global__ __launch_bounds__(256) void finalize_kernel(
    const float* __restrict__ exist, const float* __restrict__ mu,
    const float* __restrict__ logvar, const float* __restrict__ mean,
    const float* __restrict__ trans, const float* __restrict__ recpart,
    const float* __restrict__ colpart, float* __restrict__ out)
{
    const int t = threadIdx.x;
    __shared__ float scol[NB*NK];
    __shared__ double red[256];

    // column sums: colsum[b][k] = sum over 16 chunks of colpart[(b*16+c)*16 + k]
    for (int i = t; i < NB*NK; i += 256) {
        int b = i >> 4, k = i & 15;
        float s = 0.f;
        #pragma unroll
        for (int c = 0; c < 16; ++c) s += colpart[(b*16 + c)*16 + k];
        scol[i] = s;
    }
    __syncthreads();

    double acc = 0.0;

    // KLD: mean_b( -0.5 * sum_d(1 + lv - mu^2 - e^lv) )
    for (int i = t; i < NB*ND; i += 256) {
        float lv = logvar[i], m = mu[i];
        acc += (double)(-0.5f * (1.0f + lv - m*m - expf(lv))) * (W_KLD / (double)NB);
    }

    // EXT + CST + REC over 512 per-(b,k)/per-block slots
    for (int i = t; i < NB*NK; i += 256) {
        float l  = exist[i];
        float gt = (scol[i] > 24.0f) ? 1.0f : 0.0f;
        float ext = fmaxf(l, 0.f) - l*gt + log1pf(expf(-fabsf(l)));
        acc += (double)ext * (W_EXT / (double)(NB*NK));

        float dx = mean[i*3+0] - trans[i*3+0];
        float dy = mean[i*3+1] - trans[i*3+1];
        float dz = mean[i*3+2] - trans[i*3+2];
        acc += (double)sqrtf(dx*dx + dy*dy + dz*dz) * (W_CST / (double)(NB*NK));

        acc += (double)recpart[i] * (W_REC / ((double)NB * (double)NN));
    }

    // SPS: mean_b( (mean_k sqrt(colsum/N + 0.01))^2 )
    if (t < NB) {
        float sm = 0.f;
        #pragma unroll
        for (int k = 0; k < NK; ++k)
            sm += sqrtf(scol[t*NK + k] * (1.0f/(float)NN) + 0.01f);
        sm *= (1.0f/(float)NK);
        acc += (double)(sm*sm) * (W_SPS / (double)NB);
    }

    red[t] = acc;
    __syncthreads();
    for (int s2 = 128; s2; s2 >>= 1) {
        if (t < s2) red[t] += red[t + s2];
        __syncthreads();
    }
    if (t == 0) out[0] = (float)red[0];
}

extern "C" void kernel_launch(void* const* d_in, const int* in_sizes, int n_in,
                              void* d_out, int out_size, void* d_ws, size_t ws_size,
                              hipStream_t stream) {
    const float* pc      = (const float*)d_in[0];
    const float* normals = (const float*)d_in[1];
    const float* rnd     = (const float*)d_in[2];
    const float* scale   = (const float*)d_in[3];
    const float* shapes  = (const float*)d_in[4];
    const float* rotate  = (const float*)d_in[5];
    const float* mean    = (const float*)d_in[6];
    const float* assign  = (const float*)d_in[7];
    const float* exist   = (const float*)d_in[8];
    const float* mu      = (const float*)d_in[9];
    const float* logvar  = (const float*)d_in[10];
    const float* trans   = (const float*)d_in[11];

    float* recpart = (float*)d_ws;            // 512 floats, all written each call
    float* colpart = recpart + NB*16;         // 512*16 floats, all written each call

    rec_kernel<<<dim3(NB*16), dim3(256), 0, stream>>>(
        pc, normals, rnd, scale, shapes, rotate, mean, assign, recpart, colpart);
    finalize_kernel<<<dim3(1), dim3(256), 0, stream>>>(
        exist, mu, logvar, mean, trans, recpart, colpart, (float*)d_out);
}

// Round 4
// 100.178 us; speedup vs baseline: 1.5793x; 1.0929x over previous
//
#include <hip/hip_runtime.h>
#include <math.h>

#define NB 32
#define NN 4096
#define NK 16
#define ND 128
#define KPT 4            // k's per thread
#define NKG (NK/KPT)     // 4 k-groups
#define NCHUNK 16        // 256-point chunks per batch
#define NBLK (NB*NCHUNK*NKG)   // 2048 blocks

#define W_STD 0.01f
#define W_REC 1.0
#define W_SPS 0.1
#define W_EXT 0.01
#define W_KLD 0.001
#define W_CST 0.1

__device__ __forceinline__ float flog2(float x) { return __builtin_amdgcn_logf(x); }
__device__ __forceinline__ float fexp2(float x) { return __builtin_amdgcn_exp2f(x); }
__device__ __forceinline__ float frsq (float x) { return __builtin_amdgcn_rsqf(x); }

// block = (b, chunk, kg): 256 threads = 256 points, each doing 4 k's.
__global__ __launch_bounds__(256) void rec_kernel(
    const float* __restrict__ pc, const float* __restrict__ normals,
    const float* __restrict__ rnd, const float* __restrict__ scale,
    const float* __restrict__ shapes, const float* __restrict__ rotate,
    const float* __restrict__ mean, const float* __restrict__ assign,
    float* __restrict__ recpart, float* __restrict__ colpart)
{
    const int bid   = blockIdx.x;
    const int b     = bid >> 6;
    const int chunk = (bid >> 2) & 15;
    const int kg    = bid & 3;
    const int t     = threadIdx.x;
    const int n     = chunk * 256 + t;

    __shared__ float sR[KPT*9], sS[KPT*3], sE[KPT*2], sM[KPT*3];
    __shared__ float csum[4][KPT];
    __shared__ float wsum[4];

    {   // 68 param floats for this (b, kg)
        const int i = t;
        if (i < 36)      sR[i]    = rotate[b*144 + kg*36 + i];
        else if (i < 48) sS[i-36] = scale [b*48  + kg*12 + (i-36)];
        else if (i < 56) sE[i-48] = shapes[b*32  + kg*8  + (i-48)];
        else if (i < 68) sM[i-56] = mean  [b*48  + kg*12 + (i-56)];
    }
    __syncthreads();

    const long pbase = (long)(b*NN + n);
    const float px = pc[pbase*3+0], py = pc[pbase*3+1], pz = pc[pbase*3+2];
    const float nx = normals[pbase*3+0], ny = normals[pbase*3+1], nz = normals[pbase*3+2];

    const float nn2 = nx*nx + ny*ny + nz*nz;
    const float inn = frsq(nn2);
    const float ux = nx*inn, uy = ny*inn, uz = nz*inn;       // unit normal
    const float c_n = rnd[pbase] * W_STD * (nn2 * inn);      // noise * ||n||

    const float4 av = *(const float4*)(assign + pbase*16 + kg*4);
    float a[KPT] = {av.x, av.y, av.z, av.w};

    const int wave = t >> 6, lane = t & 63;
    float rec = 0.f;

    #pragma unroll
    for (int kk = 0; kk < KPT; ++kk) {
        const float R0 = sR[kk*9+0], R1 = sR[kk*9+1], R2 = sR[kk*9+2];
        const float R3 = sR[kk*9+3], R4 = sR[kk*9+4], R5 = sR[kk*9+5];
        const float R6 = sR[kk*9+6], R7 = sR[kk*9+7], R8 = sR[kk*9+8];
        const float cx = sM[kk*3], cy = sM[kk*3+1], cz = sM[kk*3+2];
        const float s0 = sS[kk*3], s1 = sS[kk*3+1], s2 = sS[kk*3+2];
        const float e0 = sE[kk*2], e1 = sE[kk*2+1];

        // pci = R^T (pc - mean)
        const float dx0 = px-cx, dy0 = py-cy, dz0 = pz-cz;
        const float pcx = R0*dx0 + R3*dy0 + R6*dz0;
        const float pcy = R1*dx0 + R4*dy0 + R7*dz0;
        const float pcz = R2*dx0 + R5*dy0 + R8*dz0;
        // ni = R^T unit_normal
        const float nix = R0*ux + R3*uy + R6*uz;
        const float niy = R1*ux + R4*uy + R7*uz;
        const float niz = R2*ux + R5*uy + R8*uz;
        // psi = pci + (noise*||n||) * ni
        const float psx = fmaf(c_n, nix, pcx);
        const float psy = fmaf(c_n, niy, pcy);
        const float psz = fmaf(c_n, niz, pcz);

        // argmax over [-nix, nix, -niy, niy, -niz, niz], first-max wins
        float best = -nix; int idx = 0;
        if ( nix > best) { best =  nix; idx = 1; }
        if (-niy > best) { best = -niy; idx = 2; }
        if ( niy > best) { best =  niy; idx = 3; }
        if (-niz > best) { best = -niz; idx = 4; }
        if ( niz > best) { best =  niz; idx = 5; }

        float sx = fminf(fmaxf(psx, -s0), s0);
        float sy = fminf(fmaxf(psy, -s1), s1);
        float sz = fminf(fmaxf(psz, -s2), s2);
        const float sgn = (idx & 1) ? 1.f : -1.f;
        const int axis = idx >> 1;
        if (axis == 0)      sx = sgn*s0;
        else if (axis == 1) sy = sgn*s1;
        else                sz = sgn*s2;

        // log2-space superquadric point:
        //   X = copysign(s0 * |cphi|^e0 * |ct|^e1, sx), etc.
        //   log2|ct| = log2|sx| - L_hx/2 ; log2(cphi) = (L_hx - L_r3)/2 ...
        const float hx  = sx*sx + sy*sy;
        const float r3  = hx + sz*sz;          // >= min(scale)^2 >= 0.01
        const float Lhx = flog2(hx);
        const float Lr3 = flog2(r3);
        const float Lx  = flog2(fabsf(sx));
        const float Ly  = flog2(fabsf(sy));
        const float Lz  = flog2(fabsf(sz));

        const float e0Lc = e0 * (0.5f*(Lhx - Lr3));
        const float aX = fmaf(e1, fmaf(-0.5f, Lhx, Lx), e0Lc);
        const float aY = fmaf(e1, fmaf(-0.5f, Lhx, Ly), e0Lc);
        const float aZ = e0 * fmaf(-0.5f, Lr3, Lz);

        const float X = copysignf(s0 * fexp2(aX), sx);
        const float Y = copysignf(s1 * fexp2(aY), sy);
        const float Z = copysignf(s2 * fexp2(aZ), sz);

        const float ddx = X-pcx, ddy = Y-pcy, ddz = Z-pcz;
        rec = fmaf(ddx*ddx + ddy*ddy + ddz*ddz, a[kk], rec);
    }

    // block-reduce rec (wave butterfly then cross-wave)
    #pragma unroll
    for (int o = 32; o; o >>= 1) rec += __shfl_xor(rec, o);
    if (lane == 0) wsum[wave] = rec;

    // column-sum partials for this block's 4 k's
    #pragma unroll
    for (int kk = 0; kk < KPT; ++kk) {
        float v = a[kk];
        #pragma unroll
        for (int o = 32; o; o >>= 1) v += __shfl_xor(v, o);
        if (lane == 0) csum[wave][kk] = v;
    }
    __syncthreads();
    if (t == 0) recpart[bid] = wsum[0] + wsum[1] + wsum[2] + wsum[3];
    if (t < KPT) colpart[bid*KPT + t] = csum[0][t] + csum[1][t] + csum[2][t] + csum[3][t];
}

// Single block: column sums -> SPS/EXT; KLD; CST; REC sum; weighted combine.
__global__ __launch_bounds__(256) void finalize_kernel(
    const float* __restrict__ exist, const float* __restrict__ mu,
    const float* __restrict__ logvar, const float* __restrict__ mean,
    const float* __restrict__ trans, const float* __restrict__ recpart,
    const float* __restrict__ colpart, float* __restrict__ out)
{
    const int t = threadIdx.x;
    __shared__ float scol[NB*NK];
    __shared__ double red[256];

    // colsum[b][k] = sum over 16 chunks of colpart[((b*16+c)*4 + k/4)*4 + k%4]
    for (int i = t; i < NB*NK; i += 256) {
        int b = i >> 4, k = i & 15;
        float s = 0.f;
        #pragma unroll
        for (int c = 0; c < NCHUNK; ++c)
            s += colpart[(((b*NCHUNK + c)*NKG) + (k >> 2))*KPT + (k & 3)];
        scol[i] = s;
    }
    __syncthreads();

    double acc = 0.0;

    // KLD
    for (int i = t; i < NB*ND; i += 256) {
        float lv = logvar[i], m = mu[i];
        acc += (double)(-0.5f * (1.0f + lv - m*m - expf(lv))) * (W_KLD / (double)NB);
    }

    // EXT + CST over 512 (b,k) slots
    for (int i = t; i < NB*NK; i += 256) {
        float l  = exist[i];
        float gt = (scol[i] > 24.0f) ? 1.0f : 0.0f;
        float ext = fmaxf(l, 0.f) - l*gt + log1pf(expf(-fabsf(l)));
        acc += (double)ext * (W_EXT / (double)(NB*NK));

        float dx = mean[i*3+0] - trans[i*3+0];
        float dy = mean[i*3+1] - trans[i*3+1];
        float dz = mean[i*3+2] - trans[i*3+2];
        acc += (double)sqrtf(dx*dx + dy*dy + dz*dz) * (W_CST / (double)(NB*NK));
    }

    // REC over 2048 block partials
    for (int i = t; i < NBLK; i += 256)
        acc += (double)recpart[i] * (W_REC / ((double)NB * (double)NN));

    // SPS
    if (t < NB) {
        float sm = 0.f;
        #pragma unroll
        for (int k = 0; k < NK; ++k)
            sm += sqrtf(scol[t*NK + k] * (1.0f/(float)NN) + 0.01f);
        sm *= (1.0f/(float)NK);
        acc += (double)(sm*sm) * (W_SPS / (double)NB);
    }

    red[t] = acc;
    __syncthreads();
    for (int s2 = 128; s2; s2 >>= 1) {
        if (t < s2) red[t] += red[t + s2];
        __syncthreads();
    }
    if (t == 0) out[0] = (float)red[0];
}

extern "C" void kernel_launch(void* const* d_in, const int* in_sizes, int n_in,
                              void* d_out, int out_size, void* d_ws, size_t ws_size,
                              hipStream_t stream) {
    const float* pc      = (const float*)d_in[0];
    const float* normals = (const float*)d_in[1];
    const float* rnd     = (const float*)d_in[2];
    const float* scale   = (const float*)d_in[3];
    const float* shapes  = (const float*)d_in[4];
    const float* rotate  = (const float*)d_in[5];
    const float* mean    = (const float*)d_in[6];
    const float* assign  = (const float*)d_in[7];
    const float* exist   = (const float*)d_in[8];
    const float* mu      = (const float*)d_in[9];
    const float* logvar  = (const float*)d_in[10];
    const float* trans   = (const float*)d_in[11];

    float* recpart = (float*)d_ws;            // NBLK floats, all written each call
    float* colpart = recpart + NBLK;          // NBLK*KPT floats, all written each call

    rec_kernel<<<dim3(NBLK), dim3(256), 0, stream>>>(
        pc, normals, rnd, scale, shapes, rotate, mean, assign, recpart, colpart);
    finalize_kernel<<<dim3(1), dim3(256), 0, stream>>>(
        exist, mu, logvar, mean, trans, recpart, colpart, (float*)d_out);
}